// Round 1
// baseline (1630.479 us; speedup 1.0000x reference)
//
#include <hip/hip_runtime.h>
#include <math.h>

// Problem constants (reference: b=16, H=8, N=1024, DK=64, D=512, H_LOC=4)
#define NTOK 1024
#define SCALE 0.125f

// workspace layout (float offsets)
#define WS_TREL   0            // [4][2048]   T_rel[hl][dist], dist in 0..2046
#define WS_RWV    8192         // [16][4][1024]  rw_v[b][hl][n]
#define WS_RWU    73728        // [16][4][1024]  rw_u[b][hl][q]  (includes proj-bias term + mlp_b)
#define WS_W2     139264       // [512][4]
#define WS_B2     141312       // [4]

// output layout (float offsets): out | p_attn_g | p_attn_l
#define PG_OFF   8388608       // 16*8*1024*64
#define PL_OFF   75497472      // PG_OFF + 16*4*1024*1024

// ---------------------------------------------------------------------------
// prep0: W2[c][hl], b2[hl] (incl mlp_b), T_rel[hl][dist]
// ---------------------------------------------------------------------------
__global__ void prep0(const float* __restrict__ upw, const float* __restrict__ upb,
                      const float* __restrict__ mlw, const float* __restrict__ mlb,
                      const float* __restrict__ rpt, float* __restrict__ ws) {
    int gid = blockIdx.x * 256 + threadIdx.x;
    if (gid < 2048) {
        int c = gid >> 2, hl = gid & 3;
        const float* wrow = upw + c * 256 + hl * 64;
        const float* m = mlw + hl * 64;
        float acc = 0.f;
        #pragma unroll 8
        for (int d = 0; d < 64; ++d) acc += wrow[d] * m[d];
        ws[WS_W2 + gid] = acc;                       // layout [c*4+hl]
    } else if (gid < 2052) {
        int hl = gid - 2048;
        const float* m = mlw + hl * 64;
        float acc = mlb[hl];                         // fold mlp_b here
        #pragma unroll 8
        for (int d = 0; d < 64; ++d) acc += upb[hl * 64 + d] * m[d];
        ws[WS_B2 + hl] = acc;
    } else if (gid < 2052 + 2047 * 4) {
        int tt = gid - 2052;
        int dist = tt >> 2, hl = tt & 3;
        const float* r = rpt + dist * 256 + hl * 64;
        const float* m = mlw + hl * 64;
        float acc = 0.f;
        #pragma unroll 8
        for (int d = 0; d < 64; ++d) acc += r[d] * m[d];
        ws[WS_TREL + hl * 2048 + dist] = acc;
    }
}

// ---------------------------------------------------------------------------
// prep1: rw_v[b][hl][n] = value[b,4+hl,n,:]·mlp_w[hl]
//        rw_u[b][hl][q] = users[b,q,:]·W2[:,hl] + b2[hl]
// ---------------------------------------------------------------------------
__global__ void prep1(const float* __restrict__ value, const float* __restrict__ users,
                      const float* __restrict__ mlw, float* __restrict__ ws) {
    int t = threadIdx.x;
    int lane = t & 63, w = t >> 6;
    if (blockIdx.x < 256) {
        int wave = blockIdx.x * 4 + w;               // 0..1023, 64 rows each
        for (int r = 0; r < 64; ++r) {
            int row = wave * 64 + r;                 // (b,hl,n)
            int b = row >> 12, hl = (row >> 10) & 3, n = row & 1023;
            float v = value[(((b * 8) + 4 + hl) * 1024 + n) * 64 + lane] * mlw[hl * 64 + lane];
            for (int m = 32; m; m >>= 1) v += __shfl_xor(v, m, 64);
            if (lane == 0) ws[WS_RWV + row] = v;
        }
    } else {
        __shared__ float w2[2052];
        for (int i = t; i < 2052; i += 256) w2[i] = ws[WS_W2 + i];
        __syncthreads();
        int wave = (blockIdx.x - 256) * 4 + w;       // 0..255, 64 rows each
        for (int r = 0; r < 64; ++r) {
            int row = wave * 64 + r;                 // (b,q)
            int b = row >> 10, q = row & 1023;
            const float* ur = users + (b * 1024 + q) * 512;
            float p0 = 0.f, p1 = 0.f, p2 = 0.f, p3 = 0.f;
            #pragma unroll
            for (int j = 0; j < 8; ++j) {
                float uu = ur[lane + 64 * j];
                const float* wr = &w2[(lane + 64 * j) * 4];
                p0 += uu * wr[0]; p1 += uu * wr[1]; p2 += uu * wr[2]; p3 += uu * wr[3];
            }
            for (int m = 32; m; m >>= 1) {
                p0 += __shfl_xor(p0, m, 64); p1 += __shfl_xor(p1, m, 64);
                p2 += __shfl_xor(p2, m, 64); p3 += __shfl_xor(p3, m, 64);
            }
            if (lane == 0) {
                ws[WS_RWU + (b * 4 + 0) * 1024 + q] = p0 + w2[2048];
                ws[WS_RWU + (b * 4 + 1) * 1024 + q] = p1 + w2[2049];
                ws[WS_RWU + (b * 4 + 2) * 1024 + q] = p2 + w2[2050];
                ws[WS_RWU + (b * 4 + 3) * 1024 + q] = p3 + w2[2051];
            }
        }
    }
}

// ---------------------------------------------------------------------------
// attn_main: one block = (b,h) x 128 q-rows. fp32 vector GEMM, 8x8 blocking.
// LDS exactly 64KB: QT_s (Q^T 64x128) + SB union (K^T 64x128 / V swizzled 128x64)
// u = exp(scores) written unnormalized to final p slab; rescaled at block end.
// ---------------------------------------------------------------------------
__launch_bounds__(256, 2)
__global__ void attn_main(const float* __restrict__ Q, const float* __restrict__ K,
                          const float* __restrict__ V, const int* __restrict__ mask,
                          const float* __restrict__ ws, float* __restrict__ out) {
    __shared__ float QT_s[64 * 128];   // Q^T[d][qlocal]
    __shared__ float SB[128 * 64];     // union: K^T[d][klocal] | V swizzled [k'][chunk^kr]

    const int t = threadIdx.x;
    // XCD swizzle: 8 consecutive logical blocks (one full (b,h)) per XCD
    const int lbid = (blockIdx.x & 7) * 128 + (blockIdx.x >> 3);
    const int b = lbid >> 6, h = (lbid >> 3) & 7, qt = lbid & 7;
    const int q0 = qt * 128;
    const int qg = t >> 4, kg = t & 15;
    const bool loc = (h >= 4);
    const int hl = loc ? (h - 4) : 0;

    const float* Qb = Q + ((b * 8 + h) * 1024 + q0) * 64;
    const float* Kb = K + ((b * 8 + h) * 1024) * 64;
    const float* Vb = V + ((b * 8 + h) * 1024) * 64;
    const int*   Mb = mask + (b * 1024 + q0) * 1024;
    float* Pb = out + (loc ? (PL_OFF + ((b * 4 + hl) * 1024 + q0) * 1024)
                           : (PG_OFF + ((b * 4 + h ) * 1024 + q0) * 1024));
    float* Ob = out + ((b * 8 + h) * 1024 + q0) * 64;
    const float* rwv  = ws + WS_RWV + (b * 4 + hl) * 1024;
    const float* trel = ws + WS_TREL + hl * 2048;

    // stage Q^T (2 threads per row)
    {
        int qr = t >> 1, d0 = 32 * (t & 1);
        const float* src = Qb + qr * 64 + d0;
        #pragma unroll
        for (int i = 0; i < 8; ++i) {
            float4 vv = *(const float4*)(src + 4 * i);
            QT_s[(d0 + 4 * i + 0) * 128 + qr] = vv.x;
            QT_s[(d0 + 4 * i + 1) * 128 + qr] = vv.y;
            QT_s[(d0 + 4 * i + 2) * 128 + qr] = vv.z;
            QT_s[(d0 + 4 * i + 3) * 128 + qr] = vv.w;
        }
    }
    // per-row reweight (q part) in registers
    float rq_r[8];
    #pragma unroll
    for (int i = 0; i < 8; ++i) rq_r[i] = 0.f;
    if (loc) {
        #pragma unroll
        for (int i = 0; i < 8; ++i) {
            int qq = 8 * qg + i;
            rq_r[i] = ws[WS_RWV + (b * 4 + hl) * 1024 + q0 + qq]
                    + ws[WS_RWU + (b * 4 + hl) * 1024 + q0 + qq];
        }
    }

    float o_[8][4];
    #pragma unroll
    for (int i = 0; i < 8; ++i)
        #pragma unroll
        for (int j = 0; j < 4; ++j) o_[i][j] = 0.f;
    float rs[8];
    #pragma unroll
    for (int i = 0; i < 8; ++i) rs[i] = 0.f;

    for (int s = 0; s < 8; ++s) {
        const int k0 = s * 128;
        __syncthreads();   // s=0: Q^T ready; s>0: prev PV done reading SB
        // ---- stage K^T ----
        {
            int kr = t >> 1, d0 = 32 * (t & 1);
            const float* src = Kb + (k0 + kr) * 64 + d0;
            #pragma unroll
            for (int i = 0; i < 8; ++i) {
                float4 vv = *(const float4*)(src + 4 * i);
                SB[(d0 + 4 * i + 0) * 128 + kr] = vv.x;
                SB[(d0 + 4 * i + 1) * 128 + kr] = vv.y;
                SB[(d0 + 4 * i + 2) * 128 + kr] = vv.z;
                SB[(d0 + 4 * i + 3) * 128 + kr] = vv.w;
            }
        }
        __syncthreads();
        // ---- QK^T: 8x8 register block ----
        float c_[8][8];
        #pragma unroll
        for (int i = 0; i < 8; ++i)
            #pragma unroll
            for (int j = 0; j < 8; ++j) c_[i][j] = 0.f;
        #pragma unroll 4
        for (int d = 0; d < 64; ++d) {
            float4 a0 = *(const float4*)&QT_s[d * 128 + 8 * qg];
            float4 a1 = *(const float4*)&QT_s[d * 128 + 8 * qg + 4];
            float4 b0 = *(const float4*)&SB[d * 128 + 8 * kg];
            float4 b1 = *(const float4*)&SB[d * 128 + 8 * kg + 4];
            float aa[8] = {a0.x, a0.y, a0.z, a0.w, a1.x, a1.y, a1.z, a1.w};
            float bb[8] = {b0.x, b0.y, b0.z, b0.w, b1.x, b1.y, b1.z, b1.w};
            #pragma unroll
            for (int i = 0; i < 8; ++i)
                #pragma unroll
                for (int j = 0; j < 8; ++j)
                    c_[i][j] = fmaf(aa[i], bb[j], c_[i][j]);
        }
        // ---- epilogue: u = exp(scale*s + reweight), masked -> 0 ----
        float rvv[8];
        #pragma unroll
        for (int j = 0; j < 8; ++j) rvv[j] = 0.f;
        if (loc) {
            float4 rv0 = *(const float4*)(rwv + k0 + 8 * kg);
            float4 rv1 = *(const float4*)(rwv + k0 + 8 * kg + 4);
            rvv[0] = rv0.x; rvv[1] = rv0.y; rvv[2] = rv0.z; rvv[3] = rv0.w;
            rvv[4] = rv1.x; rvv[5] = rv1.y; rvv[6] = rv1.z; rvv[7] = rv1.w;
        }
        #pragma unroll
        for (int i = 0; i < 8; ++i) {
            int qq = 8 * qg + i;
            const int* mrow = Mb + qq * 1024 + k0 + 8 * kg;
            int4 m0 = *(const int4*)mrow;
            int4 m1 = *(const int4*)(mrow + 4);
            int mm[8] = {m0.x, m0.y, m0.z, m0.w, m1.x, m1.y, m1.z, m1.w};
            float tadd[8];
            if (loc) {
                const float* tb = trel + 1023 + k0 + 8 * kg - (q0 + qq);
                #pragma unroll
                for (int j = 0; j < 8; ++j) tadd[j] = rq_r[i] + tb[j] + rvv[j];
            } else {
                #pragma unroll
                for (int j = 0; j < 8; ++j) tadd[j] = 0.f;
            }
            float u[8];
            #pragma unroll
            for (int j = 0; j < 8; ++j) {
                float sc = fmaf(c_[i][j], SCALE, tadd[j]);
                u[j] = (mm[j] != 0) ? __expf(sc) : 0.f;
            }
            rs[i] += ((u[0] + u[1]) + (u[2] + u[3])) + ((u[4] + u[5]) + (u[6] + u[7]));
            float* prow = Pb + qq * 1024 + k0 + 8 * kg;
            *(float4*)prow       = make_float4(u[0], u[1], u[2], u[3]);
            *(float4*)(prow + 4) = make_float4(u[4], u[5], u[6], u[7]);
        }
        __syncthreads();   // K^T dead; u writes drained (syncthreads waits vmcnt(0))
        // ---- stage V (XOR-swizzled chunks, stride 64) ----
        {
            int kr = t >> 1, d0 = 32 * (t & 1);
            const float* src = Vb + (k0 + kr) * 64 + d0;
            #pragma unroll
            for (int i = 0; i < 8; ++i) {
                float4 vv = *(const float4*)(src + 4 * i);
                int cc = (d0 >> 2) + i;
                int ccs = cc ^ (kr & 7);
                *(float4*)&SB[kr * 64 + 4 * ccs] = vv;
            }
        }
        __syncthreads();
        // ---- PV: o += u (global, L1/L2-hot) * V (LDS) ----
        #pragma unroll 2
        for (int kk = 0; kk < 128; kk += 4) {
            float4 v0 = *(const float4*)&SB[(kk + 0) * 64 + 4 * (kg ^ ((kk + 0) & 7))];
            float4 v1 = *(const float4*)&SB[(kk + 1) * 64 + 4 * (kg ^ ((kk + 1) & 7))];
            float4 v2 = *(const float4*)&SB[(kk + 2) * 64 + 4 * (kg ^ ((kk + 2) & 7))];
            float4 v3 = *(const float4*)&SB[(kk + 3) * 64 + 4 * (kg ^ ((kk + 3) & 7))];
            #pragma unroll
            for (int i = 0; i < 8; ++i) {
                float4 uu = *(const float4*)(Pb + (8 * qg + i) * 1024 + k0 + kk);
                o_[i][0] = fmaf(uu.x, v0.x, fmaf(uu.y, v1.x, fmaf(uu.z, v2.x, fmaf(uu.w, v3.x, o_[i][0]))));
                o_[i][1] = fmaf(uu.x, v0.y, fmaf(uu.y, v1.y, fmaf(uu.z, v2.y, fmaf(uu.w, v3.y, o_[i][1]))));
                o_[i][2] = fmaf(uu.x, v0.z, fmaf(uu.y, v1.z, fmaf(uu.z, v2.z, fmaf(uu.w, v3.z, o_[i][2]))));
                o_[i][3] = fmaf(uu.x, v0.w, fmaf(uu.y, v1.w, fmaf(uu.z, v2.w, fmaf(uu.w, v3.w, o_[i][3]))));
            }
        }
    }
    __syncthreads();   // PV done reading SB -> reuse as sums/inv scratch
    // ---- row sums (16-lane groups hold one row's k-groups) ----
    #pragma unroll
    for (int i = 0; i < 8; ++i) {
        float v = rs[i];
        v += __shfl_xor(v, 1, 16); v += __shfl_xor(v, 2, 16);
        v += __shfl_xor(v, 4, 16); v += __shfl_xor(v, 8, 16);
        if (kg == 0) SB[8 * qg + i] = v;
    }
    __syncthreads();
    if (t < 128) {
        float sm = SB[t];
        SB[t]       = (sm > 0.f) ? (1.f / sm) : 0.f;           // inv
        SB[128 + t] = (sm > 0.f) ? 0.f : (1.f / 1024.f);       // all-masked fallback (uniform)
    }
    __syncthreads();
    // ---- rescale p in place (coalesced: one row per iteration) ----
    for (int it = 0; it < 128; ++it) {
        float inv = SB[it], add = SB[128 + it];
        float4* pp = (float4*)(Pb + it * 1024) + t;
        float4 uu = *pp;
        uu.x = fmaf(uu.x, inv, add); uu.y = fmaf(uu.y, inv, add);
        uu.z = fmaf(uu.z, inv, add); uu.w = fmaf(uu.w, inv, add);
        *pp = uu;
    }
    // ---- out ----
    #pragma unroll
    for (int i = 0; i < 8; ++i) {
        int qq = 8 * qg + i;
        float inv = SB[qq];
        *(float4*)(Ob + qq * 64 + 4 * kg) =
            make_float4(o_[i][0] * inv, o_[i][1] * inv, o_[i][2] * inv, o_[i][3] * inv);
    }
}

// ---------------------------------------------------------------------------
extern "C" void kernel_launch(void* const* d_in, const int* in_sizes, int n_in,
                              void* d_out, int out_size, void* d_ws, size_t ws_size,
                              hipStream_t stream) {
    (void)in_sizes; (void)n_in; (void)out_size; (void)ws_size;
    const float* q     = (const float*)d_in[0];
    const float* k     = (const float*)d_in[1];
    const float* v     = (const float*)d_in[2];
    const int*   mask  = (const int*)  d_in[3];
    const float* users = (const float*)d_in[4];
    const float* rpt   = (const float*)d_in[5];
    const float* upw   = (const float*)d_in[6];
    const float* upb   = (const float*)d_in[7];
    const float* mlw   = (const float*)d_in[8];
    const float* mlb   = (const float*)d_in[9];
    float* ws  = (float*)d_ws;
    float* out = (float*)d_out;

    hipLaunchKernelGGL(prep0, dim3(40),   dim3(256), 0, stream, upw, upb, mlw, mlb, rpt, ws);
    hipLaunchKernelGGL(prep1, dim3(320),  dim3(256), 0, stream, v, users, mlw, ws);
    hipLaunchKernelGGL(attn_main, dim3(1024), dim3(256), 0, stream, q, k, v, mask, ws, out);
}

// Round 2
// 1559.403 us; speedup vs baseline: 1.0456x; 1.0456x over previous
//
#include <hip/hip_runtime.h>
#include <math.h>

#define L2E  1.4426950408889634f
#define QSC  (0.125f * L2E)

typedef float  f32x4 __attribute__((ext_vector_type(4)));
typedef short  s16x8 __attribute__((ext_vector_type(8)));

// ws float offsets
#define WS_TREL 0            // [4][2048] trel * L2E
#define WS_RWV  8192         // [16][4][1024] * L2E
#define WS_RWU  73728        // [16][4][1024] * L2E (incl bias terms)
#define WS_W2   139264       // [512][4]
#define WS_B2   141312       // [4]
#define WS_PM   141320       // u64 packed mask [16][1024][16], byte off 565280 (8B aligned)

// output layout (float offsets): out | p_attn_g | p_attn_l
#define PG_OFF 8388608
#define PL_OFF 75497472

// ---------------------------------------------------------------------------
__global__ void prep0(const float* __restrict__ upw, const float* __restrict__ upb,
                      const float* __restrict__ mlw, const float* __restrict__ mlb,
                      const float* __restrict__ rpt, float* __restrict__ ws) {
    int gid = blockIdx.x * 256 + threadIdx.x;
    if (gid < 2048) {
        int c = gid >> 2, hl = gid & 3;
        const float* wrow = upw + c * 256 + hl * 64;
        const float* m = mlw + hl * 64;
        float acc = 0.f;
        #pragma unroll 8
        for (int d = 0; d < 64; ++d) acc += wrow[d] * m[d];
        ws[WS_W2 + gid] = acc;
    } else if (gid < 2052) {
        int hl = gid - 2048;
        const float* m = mlw + hl * 64;
        float acc = mlb[hl];
        #pragma unroll 8
        for (int d = 0; d < 64; ++d) acc += upb[hl * 64 + d] * m[d];
        ws[WS_B2 + hl] = acc;
    } else if (gid < 2052 + 2047 * 4) {
        int tt = gid - 2052;
        int dist = tt >> 2, hl = tt & 3;
        const float* r = rpt + dist * 256 + hl * 64;
        const float* m = mlw + hl * 64;
        float acc = 0.f;
        #pragma unroll 8
        for (int d = 0; d < 64; ++d) acc += r[d] * m[d];
        ws[WS_TREL + hl * 2048 + dist] = acc * L2E;
    }
}

// ---------------------------------------------------------------------------
__global__ void prep1(const float* __restrict__ value, const float* __restrict__ users,
                      const float* __restrict__ mlw, float* __restrict__ ws) {
    int t = threadIdx.x;
    int lane = t & 63, w = t >> 6;
    if (blockIdx.x < 256) {
        int wave = blockIdx.x * 4 + w;
        for (int r = 0; r < 64; ++r) {
            int row = wave * 64 + r;
            int b = row >> 12, hl = (row >> 10) & 3, n = row & 1023;
            float v = value[(((b * 8) + 4 + hl) * 1024 + n) * 64 + lane] * mlw[hl * 64 + lane];
            for (int m = 32; m; m >>= 1) v += __shfl_xor(v, m, 64);
            if (lane == 0) ws[WS_RWV + row] = v * L2E;
        }
    } else {
        __shared__ float w2[2052];
        for (int i = t; i < 2052; i += 256) w2[i] = ws[WS_W2 + i];
        __syncthreads();
        int wave = (blockIdx.x - 256) * 4 + w;
        for (int r = 0; r < 64; ++r) {
            int row = wave * 64 + r;
            int b = row >> 10, q = row & 1023;
            const float* ur = users + (b * 1024 + q) * 512;
            float p0 = 0.f, p1 = 0.f, p2 = 0.f, p3 = 0.f;
            #pragma unroll
            for (int j = 0; j < 8; ++j) {
                float uu = ur[lane + 64 * j];
                const float* wr = &w2[(lane + 64 * j) * 4];
                p0 += uu * wr[0]; p1 += uu * wr[1]; p2 += uu * wr[2]; p3 += uu * wr[3];
            }
            for (int m = 32; m; m >>= 1) {
                p0 += __shfl_xor(p0, m, 64); p1 += __shfl_xor(p1, m, 64);
                p2 += __shfl_xor(p2, m, 64); p3 += __shfl_xor(p3, m, 64);
            }
            if (lane == 0) {
                ws[WS_RWU + (b * 4 + 0) * 1024 + q] = (p0 + w2[2048]) * L2E;
                ws[WS_RWU + (b * 4 + 1) * 1024 + q] = (p1 + w2[2049]) * L2E;
                ws[WS_RWU + (b * 4 + 2) * 1024 + q] = (p2 + w2[2050]) * L2E;
                ws[WS_RWU + (b * 4 + 3) * 1024 + q] = (p3 + w2[2051]) * L2E;
            }
        }
    }
}

// ---------------------------------------------------------------------------
// packm: mask int32 -> bit-packed u64 [16*1024 rows][16 words]
// ---------------------------------------------------------------------------
__global__ void packm(const int* __restrict__ mask, unsigned long long* __restrict__ pm) {
    int t = threadIdx.x, lane = t & 63, w = t >> 6;
    int blk = blockIdx.x;
    for (int i = w; i < 256; i += 4) {
        int row = blk * 16 + (i >> 4);
        int seg = i & 15;
        int v = mask[row * 1024 + seg * 64 + lane];
        unsigned long long bits = __ballot(v != 0);
        if (lane == 0) pm[row * 16 + seg] = bits;
    }
}

// ---------------------------------------------------------------------------
// LDS addressing: rows padded to 72 shorts (144B), 16B-chunk XOR swizzle
// ---------------------------------------------------------------------------
__device__ __forceinline__ int lswz(int row, int chunk) {
    return (((chunk ^ (row & 7)) + (row >> 3)) & 7);
}
__device__ __forceinline__ s16x8 ldsfrag(const short* base, int row, int chunk) {
    const char* p = (const char*)base + row * 144 + lswz(row, chunk) * 16;
    return *(const s16x8*)p;
}

// ---------------------------------------------------------------------------
// fused attention: pass A (row sums), pass B (p write + PV), MFMA bf16 hi/lo
// ---------------------------------------------------------------------------
__launch_bounds__(256, 3)
__global__ void attn_fused(const float* __restrict__ Q, const float* __restrict__ K,
                           const float* __restrict__ V, const float* __restrict__ ws,
                           float* __restrict__ out) {
    __shared__ __align__(16) short BufKhi[64 * 72];
    __shared__ __align__(16) short BufKlo[64 * 72];
    __shared__ __align__(16) short BufV [64 * 72];
    __shared__ __align__(16) short BufP [128 * 72];

    const int t = threadIdx.x;
    const int lbid = (blockIdx.x & 7) * 128 + (blockIdx.x >> 3);   // XCD swizzle
    const int b = lbid >> 6, h = (lbid >> 3) & 7, qt = lbid & 7;
    const int q0 = qt * 128;
    const int l = t & 63, n16 = l & 15, g = l >> 4;
    const int wq0 = (t >> 6) * 32;
    const bool loc = (h >= 4);
    const int hl = loc ? h - 4 : 0;

    const float* Qb = Q + ((b * 8 + h) * 1024 + q0) * 64;
    const float* Kb = K + ((b * 8 + h) * 1024) * 64;
    const float* Vb = V + ((b * 8 + h) * 1024) * 64;
    const unsigned long long* pm =
        ((const unsigned long long*)(ws + WS_PM)) + (size_t)b * 1024 * 16;
    const float* trel = ws + WS_TREL + hl * 2048;
    const float* rwvk = ws + WS_RWV + (b * 4 + hl) * 1024;
    const float* rwuq = ws + WS_RWU + (b * 4 + hl) * 1024;

    // ---- Q fragments (prescaled by 0.125*log2e, hi/lo split) in registers ----
    s16x8 qh[2][2], ql[2][2];
    #pragma unroll
    for (int mt = 0; mt < 2; ++mt)
      #pragma unroll
      for (int kc = 0; kc < 2; ++kc) {
        const float* qp = Qb + (wq0 + mt * 16 + n16) * 64 + kc * 32 + g * 8;
        float4 a = *(const float4*)qp;
        float4 c = *(const float4*)(qp + 4);
        float xs[8] = {a.x, a.y, a.z, a.w, c.x, c.y, c.z, c.w};
        s16x8 vh, vl;
        #pragma unroll
        for (int e = 0; e < 8; ++e) {
            float x = xs[e] * QSC;
            unsigned u = __float_as_uint(x);
            vh[e] = (short)(u >> 16);
            float hf = __uint_as_float(u & 0xFFFF0000u);
            vl[e] = (short)(__float_as_uint(x - hf) >> 16);
        }
        qh[mt][kc] = vh; ql[mt][kc] = vl;
      }

    // per-row reweight (q-dependent part)
    float rq[2][4];
    #pragma unroll
    for (int mt = 0; mt < 2; ++mt)
      #pragma unroll
      for (int r = 0; r < 4; ++r) {
        int qg = q0 + wq0 + mt * 16 + g * 4 + r;
        rq[mt][r] = loc ? (rwvk[qg] + rwuq[qg]) : 0.f;
      }

    // =============================== PASS A ===============================
    float rs[2][4] = {{0.f,0.f,0.f,0.f},{0.f,0.f,0.f,0.f}};
    for (int s = 0; s < 16; ++s) {
        const int k0 = s * 64;
        __syncthreads();
        #pragma unroll
        for (int it = 0; it < 4; ++it) {
            int kr = (t >> 4) + it * 16;
            int d0 = (t & 15) * 4;
            float4 kv = *(const float4*)(Kb + (k0 + kr) * 64 + d0);
            float xk[4] = {kv.x, kv.y, kv.z, kv.w};
            unsigned hh[4], llo[4];
            #pragma unroll
            for (int e = 0; e < 4; ++e) {
                unsigned u = __float_as_uint(xk[e]);
                hh[e] = u >> 16;
                float hf = __uint_as_float(u & 0xFFFF0000u);
                llo[e] = __float_as_uint(xk[e] - hf) >> 16;
            }
            uint2 wh = make_uint2(hh[0] | (hh[1] << 16), hh[2] | (hh[3] << 16));
            uint2 wl = make_uint2(llo[0] | (llo[1] << 16), llo[2] | (llo[3] << 16));
            int off = kr * 144 + lswz(kr, d0 >> 3) * 16 + (d0 & 7) * 2;
            *(uint2*)((char*)BufKhi + off) = wh;
            *(uint2*)((char*)BufKlo + off) = wl;
        }
        __syncthreads();

        f32x4 acc[2][4];
        #pragma unroll
        for (int mt = 0; mt < 2; ++mt)
          #pragma unroll
          for (int nt = 0; nt < 4; ++nt) acc[mt][nt] = (f32x4){0.f,0.f,0.f,0.f};
        #pragma unroll
        for (int kc = 0; kc < 2; ++kc)
          #pragma unroll
          for (int nt = 0; nt < 4; ++nt) {
            s16x8 kh = ldsfrag(BufKhi, nt * 16 + n16, kc * 4 + g);
            s16x8 kl = ldsfrag(BufKlo, nt * 16 + n16, kc * 4 + g);
            #pragma unroll
            for (int mt = 0; mt < 2; ++mt) {
                acc[mt][nt] = __builtin_amdgcn_mfma_f32_16x16x32_bf16(qh[mt][kc], kh, acc[mt][nt], 0, 0, 0);
                acc[mt][nt] = __builtin_amdgcn_mfma_f32_16x16x32_bf16(qh[mt][kc], kl, acc[mt][nt], 0, 0, 0);
                acc[mt][nt] = __builtin_amdgcn_mfma_f32_16x16x32_bf16(ql[mt][kc], kh, acc[mt][nt], 0, 0, 0);
            }
          }

        float rvv[4] = {0.f,0.f,0.f,0.f};
        if (loc) {
            #pragma unroll
            for (int nt = 0; nt < 4; ++nt) rvv[nt] = rwvk[k0 + nt * 16 + n16];
        }
        #pragma unroll
        for (int mt = 0; mt < 2; ++mt)
          #pragma unroll
          for (int r = 0; r < 4; ++r) {
            int qg = q0 + wq0 + mt * 16 + g * 4 + r;
            unsigned long long mb = pm[qg * 16 + s];
            const float* tb = trel + 1023 + k0 - qg;
            #pragma unroll
            for (int nt = 0; nt < 4; ++nt) {
                float sc = acc[mt][nt][r] + rq[mt][r];
                if (loc) sc += tb[nt * 16 + n16] + rvv[nt];
                float u = ((mb >> (nt * 16 + n16)) & 1ULL) ? exp2f(sc) : 0.f;
                rs[mt][r] += u;
            }
          }
    }

    // row sums -> inverse (sentinel -1 for all-masked rows), all in registers
    float inv_[2][4];
    #pragma unroll
    for (int mt = 0; mt < 2; ++mt)
      #pragma unroll
      for (int r = 0; r < 4; ++r) {
        float v = rs[mt][r];
        v += __shfl_xor(v, 1); v += __shfl_xor(v, 2);
        v += __shfl_xor(v, 4); v += __shfl_xor(v, 8);
        inv_[mt][r] = (v > 0.f) ? (1.f / v) : -1.f;
      }

    // =============================== PASS B ===============================
    f32x4 o_[2][4];
    #pragma unroll
    for (int mt = 0; mt < 2; ++mt)
      #pragma unroll
      for (int dt = 0; dt < 4; ++dt) o_[mt][dt] = (f32x4){0.f,0.f,0.f,0.f};

    float* Pb = out + (loc ? (PL_OFF + ((b * 4 + hl) * 1024 + q0) * 1024)
                           : (PG_OFF + ((b * 4 + h ) * 1024 + q0) * 1024));

    for (int s = 0; s < 16; ++s) {
        const int k0 = s * 64;
        __syncthreads();
        #pragma unroll
        for (int it = 0; it < 4; ++it) {
            int kr = (t >> 4) + it * 16;
            int d0 = (t & 15) * 4;
            float4 kv = *(const float4*)(Kb + (k0 + kr) * 64 + d0);
            float xk[4] = {kv.x, kv.y, kv.z, kv.w};
            unsigned hh[4], llo[4];
            #pragma unroll
            for (int e = 0; e < 4; ++e) {
                unsigned u = __float_as_uint(xk[e]);
                hh[e] = u >> 16;
                float hf = __uint_as_float(u & 0xFFFF0000u);
                llo[e] = __float_as_uint(xk[e] - hf) >> 16;
            }
            uint2 wh = make_uint2(hh[0] | (hh[1] << 16), hh[2] | (hh[3] << 16));
            uint2 wl = make_uint2(llo[0] | (llo[1] << 16), llo[2] | (llo[3] << 16));
            int off = kr * 144 + lswz(kr, d0 >> 3) * 16 + (d0 & 7) * 2;
            *(uint2*)((char*)BufKhi + off) = wh;
            *(uint2*)((char*)BufKlo + off) = wl;
            // V (single bf16, RNE)
            float4 vv = *(const float4*)(Vb + (k0 + kr) * 64 + d0);
            float xv[4] = {vv.x, vv.y, vv.z, vv.w};
            #pragma unroll
            for (int e = 0; e < 4; ++e) {
                unsigned u = __float_as_uint(xv[e]);
                unsigned rr = u + 0x7FFFu + ((u >> 16) & 1u);
                int d = d0 + e;
                *(short*)((char*)BufV + d * 144 + lswz(d, kr >> 3) * 16 + (kr & 7) * 2) =
                    (short)(rr >> 16);
            }
        }
        __syncthreads();

        f32x4 acc[2][4];
        #pragma unroll
        for (int mt = 0; mt < 2; ++mt)
          #pragma unroll
          for (int nt = 0; nt < 4; ++nt) acc[mt][nt] = (f32x4){0.f,0.f,0.f,0.f};
        #pragma unroll
        for (int kc = 0; kc < 2; ++kc)
          #pragma unroll
          for (int nt = 0; nt < 4; ++nt) {
            s16x8 kh = ldsfrag(BufKhi, nt * 16 + n16, kc * 4 + g);
            s16x8 kl = ldsfrag(BufKlo, nt * 16 + n16, kc * 4 + g);
            #pragma unroll
            for (int mt = 0; mt < 2; ++mt) {
                acc[mt][nt] = __builtin_amdgcn_mfma_f32_16x16x32_bf16(qh[mt][kc], kh, acc[mt][nt], 0, 0, 0);
                acc[mt][nt] = __builtin_amdgcn_mfma_f32_16x16x32_bf16(qh[mt][kc], kl, acc[mt][nt], 0, 0, 0);
                acc[mt][nt] = __builtin_amdgcn_mfma_f32_16x16x32_bf16(ql[mt][kc], kh, acc[mt][nt], 0, 0, 0);
            }
          }

        float rvv[4] = {0.f,0.f,0.f,0.f};
        if (loc) {
            #pragma unroll
            for (int nt = 0; nt < 4; ++nt) rvv[nt] = rwvk[k0 + nt * 16 + n16];
        }
        #pragma unroll
        for (int mt = 0; mt < 2; ++mt)
          #pragma unroll
          for (int r = 0; r < 4; ++r) {
            int qloc = wq0 + mt * 16 + g * 4 + r;
            int qg = q0 + qloc;
            unsigned long long mb = pm[qg * 16 + s];
            const float* tb = trel + 1023 + k0 - qg;
            float iv = inv_[mt][r];
            #pragma unroll
            for (int nt = 0; nt < 4; ++nt) {
                float sc = acc[mt][nt][r] + rq[mt][r];
                if (loc) sc += tb[nt * 16 + n16] + rvv[nt];
                float u = ((mb >> (nt * 16 + n16)) & 1ULL) ? exp2f(sc) : 0.f;
                float p = (iv > 0.f) ? u * iv : (1.f / 1024.f);
                __builtin_nontemporal_store(p, Pb + qloc * 1024 + k0 + nt * 16 + n16);
                unsigned uu = __float_as_uint(p);
                unsigned rr = uu + 0x7FFFu + ((uu >> 16) & 1u);
                int kl_ = nt * 16 + n16;
                *(short*)((char*)BufP + qloc * 144 + lswz(qloc, kl_ >> 3) * 16 + (kl_ & 7) * 2) =
                    (short)(rr >> 16);
            }
          }

        // PV: o += p(bf16, LDS) * V(bf16, LDS)
        #pragma unroll
        for (int kc = 0; kc < 2; ++kc) {
            s16x8 pa0 = ldsfrag(BufP, wq0 + n16,      kc * 4 + g);
            s16x8 pa1 = ldsfrag(BufP, wq0 + 16 + n16, kc * 4 + g);
            #pragma unroll
            for (int dt = 0; dt < 4; ++dt) {
                s16x8 vb = ldsfrag(BufV, dt * 16 + n16, kc * 4 + g);
                o_[0][dt] = __builtin_amdgcn_mfma_f32_16x16x32_bf16(pa0, vb, o_[0][dt], 0, 0, 0);
                o_[1][dt] = __builtin_amdgcn_mfma_f32_16x16x32_bf16(pa1, vb, o_[1][dt], 0, 0, 0);
            }
        }
    }

    // ---- out ----
    float* Ob = out + ((b * 8 + h) * 1024 + q0) * 64;
    #pragma unroll
    for (int mt = 0; mt < 2; ++mt)
      #pragma unroll
      for (int dt = 0; dt < 4; ++dt)
        #pragma unroll
        for (int r = 0; r < 4; ++r) {
            int qloc = wq0 + mt * 16 + g * 4 + r;
            __builtin_nontemporal_store(o_[mt][dt][r], Ob + qloc * 64 + dt * 16 + n16);
        }
}

// ---------------------------------------------------------------------------
extern "C" void kernel_launch(void* const* d_in, const int* in_sizes, int n_in,
                              void* d_out, int out_size, void* d_ws, size_t ws_size,
                              hipStream_t stream) {
    (void)in_sizes; (void)n_in; (void)out_size; (void)ws_size;
    const float* q     = (const float*)d_in[0];
    const float* k     = (const float*)d_in[1];
    const float* v     = (const float*)d_in[2];
    const int*   mask  = (const int*)  d_in[3];
    const float* users = (const float*)d_in[4];
    const float* rpt   = (const float*)d_in[5];
    const float* upw   = (const float*)d_in[6];
    const float* upb   = (const float*)d_in[7];
    const float* mlw   = (const float*)d_in[8];
    const float* mlb   = (const float*)d_in[9];
    float* ws  = (float*)d_ws;
    float* out = (float*)d_out;

    hipLaunchKernelGGL(prep0, dim3(40),   dim3(256), 0, stream, upw, upb, mlw, mlb, rpt, ws);
    hipLaunchKernelGGL(prep1, dim3(320),  dim3(256), 0, stream, v, users, mlw, ws);
    hipLaunchKernelGGL(packm, dim3(1024), dim3(256), 0, stream, mask,
                       (unsigned long long*)(ws + WS_PM));
    hipLaunchKernelGGL(attn_fused, dim3(1024), dim3(256), 0, stream, q, k, v, ws, out);
}